// Round 8
// baseline (344.894 us; speedup 1.0000x reference)
//
#include <hip/hip_runtime.h>
#include <hip/hip_bf16.h>
#include <stdint.h>

typedef short    s16x8  __attribute__((ext_vector_type(8)));
typedef __bf16   bf16x8 __attribute__((ext_vector_type(8)));
typedef float    f32x4  __attribute__((ext_vector_type(4)));

__device__ __forceinline__ unsigned short f2bf(float f) {
    union { float f; unsigned u; } v; v.f = f;
    unsigned r = v.u + 0x7FFFu + ((v.u >> 16) & 1u);
    return (unsigned short)(r >> 16);
}
__device__ __forceinline__ float bf2f(unsigned short s) {
    union { unsigned u; float f; } v; v.u = ((unsigned)s) << 16;
    return v.f;
}

__device__ __forceinline__ void gload16(const void* g, void* l) {
    __builtin_amdgcn_global_load_lds(
        (const __attribute__((address_space(1))) void*)(uintptr_t)g,
        (__attribute__((address_space(3))) void*)(uintptr_t)l,
        16, 0, 0);
}

// ---------------- fp32 -> bf16 conversion (vectorized, grid-stride) ----------
__global__ __launch_bounds__(256) void cvt_bf16(const float* __restrict__ in,
                                                unsigned short* __restrict__ out,
                                                int n4) {
    int i = blockIdx.x * blockDim.x + threadIdx.x;
    int stride = gridDim.x * blockDim.x;
    for (; i < n4; i += stride) {
        const float4 v = *(const float4*)(in + (size_t)i * 4);
        ushort4 o;
        o.x = f2bf(v.x); o.y = f2bf(v.y); o.z = f2bf(v.z); o.w = f2bf(v.w);
        *(ushort4*)(out + (size_t)i * 4) = o;
    }
}

// ---------------- 4-wave 256x256 bf16 GEMM: C = A[M][K] @ B[N][K]^T + bias --
// NEW GEOMETRY: 4 waves (2x2), 128x128 C per wave (acc 8x8 frags, 256 VGPR),
// 1 wave/SIMD. A-fragments loaded DIRECTLY global->VGPR (per-lane dwordx4,
// 64-B-segment coalesced, prefetch 1 tile ahead) — A never touches LDS.
// LDS holds only B: 4-slot ring (64 KiB), T2 source-XOR swizzle (conflicts
// measured 0), counted vmcnt, T5 setprio, T1 XCD swizzle.
template<int K, bool OUT_BF16>
__global__ __launch_bounds__(256, 1) void gemm4w(
        const unsigned short* __restrict__ A,   // [M][K] bf16
        const unsigned short* __restrict__ B,   // [N][K] bf16
        const float* __restrict__ bias,         // [N] fp32
        void* __restrict__ Cvoid,               // [M][N] bf16 or fp32
        int M, int N, int ntn) {
    constexpr int BM = 256, BN = 256, BK = 32, NT = K / BK;
    __shared__ unsigned short Bs[4][BN * BK];   // 4 x 16 KiB = 64 KiB
    const int tid  = threadIdx.x;
    const int lane = tid & 63;
    const int wv   = tid >> 6;                  // 4 waves
    const int nwg  = (int)gridDim.x;
    const int wg   = ((int)blockIdx.x & 7) * (nwg >> 3) + ((int)blockIdx.x >> 3);
    const int bm   = wg / ntn;
    const int bn   = wg % ntn;
    const int wr   = (wv >> 1) * 128;   // wave M-offset in tile
    const int wc   = (wv & 1) * 128;    // wave N-offset in tile
    const int lr   = lane & 15;
    const int ls   = lane >> 4;         // k-slot 0..3

    const unsigned short* Ag = A + (size_t)bm * BM * K;
    const unsigned short* Bg = B + (size_t)bn * BN * K;

    // Stage B K-slab t (256x32 bf16 = 1024 x 16B chunks, 4 per thread).
    // Linear LDS dest; T2 swizzle pre-applied on the GLOBAL source slot.
    auto stageB = [&](int t) {
        char* lb = (char*)Bs[t & 3];
        #pragma unroll
        for (int p = 0; p < 4; ++p) {
            const int c     = p * 256 + tid;
            const int row   = c >> 2;
            const int slot  = c & 3;
            const int gslot = slot ^ ((row >> 1) & 3);
            gload16(Bg + (size_t)row * K + t * BK + gslot * 8, lb + c * 16);
        }
    };
    // B fragment from LDS: logical k-slot ls, physical = ls ^ swz(row).
    auto fragB = [&](int t, int n) -> bf16x8 {
        const int row  = wc + n * 16 + lr;
        const int slot = ls ^ ((row >> 1) & 3);
        return *(const bf16x8*)((const char*)Bs[t & 3] + row * (BK * 2) + slot * 16);
    };
    // A fragment direct from global: row wr+m*16+lr, cols t*32+ls*8..+8 (16 B).
    auto loadA = [&](int t, bf16x8* dst) {
        #pragma unroll
        for (int m = 0; m < 8; ++m)
            dst[m] = *(const bf16x8*)(Ag + (size_t)(wr + m * 16 + lr) * K
                                         + t * BK + ls * 8);
    };

    f32x4 acc[8][8] = {};
    bf16x8 af[2][8];     // A-frag double buffer (t&1 static after full unroll)
    bf16x8 bf[8];

    stageB(0); stageB(1); stageB(2);   // 12 gloads/thread in flight
    loadA(0, af[0]);                   // + 8 A loads

    #pragma unroll
    for (int t = 0; t < NT; ++t) {
        // Publish B(t): possibly-outstanding newer ops = A(t){8} + B(t+1){4}
        // + B(t+2){4} = 16 steady; tail 12 / 8. N <= outstanding-newer => safe.
        if (t <= NT - 3)      asm volatile("s_waitcnt vmcnt(16)" ::: "memory");
        else if (t == NT - 2) asm volatile("s_waitcnt vmcnt(12)" ::: "memory");
        else                  asm volatile("s_waitcnt vmcnt(8)"  ::: "memory");
        __builtin_amdgcn_s_barrier();   // all threads' B(t) chunks visible;
                                        // ring slot (t+3)&3 fully consumed
        if (t + 1 < NT) loadA(t + 1, af[(t + 1) & 1]);   // A prefetch (VGPR)
        if (t + 3 < NT) stageB(t + 3);                   // B prefetch (LDS)
        #pragma unroll
        for (int n = 0; n < 8; ++n) bf[n] = fragB(t, n);

        __builtin_amdgcn_s_setprio(1);
        #pragma unroll
        for (int n = 0; n < 8; ++n)
            #pragma unroll
            for (int m = 0; m < 8; ++m)
                acc[m][n] = __builtin_amdgcn_mfma_f32_16x16x32_bf16(
                    af[t & 1][m], bf[n], acc[m][n], 0, 0, 0);
        __builtin_amdgcn_s_setprio(0);
    }

    // epilogue: C/D layout col=lane&15, row=(lane>>4)*4+j (HW-verified).
    // Direct stores (round 7 proved the LDS-coalesced epilogue costs more
    // than the write amplification it saves).
    const int r0 = bm * BM + wr + ls * 4;
    const int c0 = bn * BN + wc + lr;
    #pragma unroll
    for (int n = 0; n < 8; ++n) {
        const int gc = c0 + n * 16;
        const float bv = bias[gc];
        #pragma unroll
        for (int m = 0; m < 8; ++m) {
            #pragma unroll
            for (int j = 0; j < 4; ++j) {
                const int gr = r0 + m * 16 + j;
                const float v = acc[m][n][j] + bv;
                if constexpr (OUT_BF16)
                    ((unsigned short*)Cvoid)[(size_t)gr * N + gc] = f2bf(v);
                else
                    ((float*)Cvoid)[(size_t)gr * N + gc] = v;
            }
        }
    }
}

// ---------------- per-token attention over heads (8x8 softmax) --------------
__global__ __launch_bounds__(256) void attn_heads(
        const unsigned short* __restrict__ qkv,   // [M][1536] bf16
        unsigned short* __restrict__ val,         // [M][512]  bf16
        int M) {
    const int t    = blockIdx.x * 4 + (threadIdx.x >> 6);
    const int lane = threadIdx.x & 63;
    const int h    = lane >> 3;
    const int c    = lane & 7;
    const unsigned short* base = qkv + (size_t)t * 1536;

    s16x8 q8 = *(const s16x8*)(base + h * 192 + c * 8);
    float qf[8];
    #pragma unroll
    for (int j = 0; j < 8; ++j) qf[j] = bf2f((unsigned short)q8[j]);

    float s[8];
    #pragma unroll
    for (int g = 0; g < 8; ++g) {
        s16x8 k8 = *(const s16x8*)(base + g * 192 + 64 + c * 8);
        float p = 0.f;
        #pragma unroll
        for (int j = 0; j < 8; ++j) p += qf[j] * bf2f((unsigned short)k8[j]);
        s[g] = p;
    }
    #pragma unroll
    for (int mask = 1; mask <= 4; mask <<= 1)
        #pragma unroll
        for (int g = 0; g < 8; ++g)
            s[g] += __shfl_xor(s[g], mask, 64);

    float mx = -1e30f;
    #pragma unroll
    for (int g = 0; g < 8; ++g) { s[g] *= 0.125f; mx = fmaxf(mx, s[g]); }
    float sum = 0.f;
    #pragma unroll
    for (int g = 0; g < 8; ++g) { s[g] = __expf(s[g] - mx); sum += s[g]; }
    const float inv = 1.f / sum;

    float acc[8] = {0.f,0.f,0.f,0.f,0.f,0.f,0.f,0.f};
    #pragma unroll
    for (int g = 0; g < 8; ++g) {
        s16x8 v8 = *(const s16x8*)(base + g * 192 + 128 + c * 8);
        const float ag = s[g] * inv;
        #pragma unroll
        for (int j = 0; j < 8; ++j) acc[j] += ag * bf2f((unsigned short)v8[j]);
    }
    s16x8 ov;
    #pragma unroll
    for (int j = 0; j < 8; ++j) ov[j] = (short)f2bf(acc[j]);
    *(s16x8*)(val + (size_t)t * 512 + h * 64 + c * 8) = ov;
}

// ---------------------------------------------------------------------------
extern "C" void kernel_launch(void* const* d_in, const int* in_sizes, int n_in,
                              void* d_out, int out_size, void* d_ws, size_t ws_size,
                              hipStream_t stream) {
    const float* x     = (const float*)d_in[0];
    const float* w_qkv = (const float*)d_in[1];
    const float* b_qkv = (const float*)d_in[2];
    const float* w_out = (const float*)d_in[3];
    const float* b_out = (const float*)d_in[4];
    float* out = (float*)d_out;

    const int DM = 512;
    const int M  = in_sizes[0] / DM;      // 61440 tokens

    unsigned short* xb    = (unsigned short*)d_ws;          // M*512
    unsigned short* wqkvb = xb + (size_t)M * DM;            // 1536*512
    unsigned short* woutb = wqkvb + (size_t)3 * DM * DM;    // 512*512
    unsigned short* qkvb  = woutb + (size_t)DM * DM;        // M*1536
    unsigned short* valb  = xb;   // reuse x_bf16 buffer after GEMM1 consumed it

    cvt_bf16<<<2048, 256, 0, stream>>>(x, xb, M * DM / 4);
    cvt_bf16<<<96,   256, 0, stream>>>(w_qkv, wqkvb, 3 * DM * DM / 4);
    cvt_bf16<<<32,   256, 0, stream>>>(w_out, woutb, DM * DM / 4);

    // GEMM1: qkv[M][1536] = x @ w_qkv^T + b_qkv (bf16 out). grid 240*6=1440
    gemm4w<512, true><<<dim3((M / 256) * (3 * DM / 256)), 256, 0, stream>>>(
        xb, wqkvb, b_qkv, qkvb, M, 3 * DM, 3 * DM / 256);

    // per-token attention over heads
    attn_heads<<<M / 4, 256, 0, stream>>>(qkvb, valb, M);

    // GEMM2: out[M][512] = val @ w_out^T + b_out (fp32 out). grid 240*2=480
    gemm4w<512, false><<<dim3((M / 256) * (DM / 256)), 256, 0, stream>>>(
        valb, woutb, b_out, out, M, DM, DM / 256);
}